// Round 7
// baseline (56.002 us; speedup 1.0000x reference)
//
#include <hip/hip_runtime.h>
#include <math.h>

#define N_PRED 12
#define B      256
#define N_NEG  128
#define D      512
#define LOG2E  1.4426950408889634f
#define LN2    0.6931471805599453f

typedef float f2 __attribute__((ext_vector_type(2)));

__device__ __forceinline__ float ex2(float x) { return __builtin_amdgcn_exp2f(x); }

// exp-sum over this lane's 16 d-elements from a preloaded register buffer.
__device__ __forceinline__ float buf16(const float4* __restrict__ y,
                                       const f2* __restrict__ p2) {
    f2 acc = {0.f, 0.f};
#pragma unroll
    for (int j = 0; j < 4; ++j) {
        f2 m0 = p2[2 * j]     * f2{y[j].x, y[j].y};
        f2 m1 = p2[2 * j + 1] * f2{y[j].z, y[j].w};
        f2 e0, e1;
        e0.x = ex2(m0.x); e0.y = ex2(m0.y);
        e1.x = ex2(m1.x); e1.y = ex2(m1.y);
        acc += e0;
        acc += e1;
    }
    return acc.x + acc.y;
}

// One block per (t,b). 4 waves. 32 lanes per neg (g = lane>>5 picks one of 2
// negs per stage, q = lane&31 the d-slice), cyclic float4 mapping q+32j so
// each load instruction covers 2 contiguous 512B segments (fully coalesced).
// 4-deep explicitly-rotated register pipeline (Y0..Y3 named — no runtime
// array indexing, rule #20) with __launch_bounds__(256,4): 128-VGPR budget
// so the compiler KEEPS the buffers live (at the default 64-reg target it
// serialized the R6 pipeline away). Load->use distance = 3 compute stages
// (~300+ cyc) -> covers L2/IC gather latency at 4 waves/SIMD.
__global__ __launch_bounds__(256, 4) void fk_kernel(
    const float* __restrict__ lp,        // (13,256,512)
    const float* __restrict__ ps,        // (12,256,512)
    const int*   __restrict__ time_idx,  // (12,256,128)
    const int*   __restrict__ batch_idx, // (12,256,128)
    float* __restrict__ per_step,        // (12*256)
    float* __restrict__ flags)           // (12*256)
{
    const int tb   = blockIdx.x;   // 0..3071
    const int t    = tb >> 8;
    const int b    = tb & (B - 1);
    const int tid  = threadIdx.x;
    const int wave = tid >> 6;
    const int lane = tid & 63;
    const int q    = lane & 31;    // d-slice within neg-group
    const int g    = lane >> 5;    // neg-group id (0..1)

    __shared__ const float* s_row[N_NEG];
    __shared__ float s_sum[4];
    __shared__ int   s_ok[4];

    // Stage per-neg row base addresses once.
    const int idx_base = (t * B + b) * N_NEG;
    if (tid < N_NEG) {
        const int ti = time_idx[idx_base + tid];
        const int bi = batch_idx[idx_base + tid];
        s_row[tid] = (ti == 0) ? (lp + (size_t)bi * D)
                               : (ps + ((size_t)(ti - 1) * B + bi) * D);
    }

    // pred slice (cyclic), pre-scaled by log2(e), as 8 packed f2 (16 VGPR).
    const float4* pred4 = (const float4*)(lp + ((size_t)(t + 1) * B + b) * D) + q;
    f2 p2[8];
#pragma unroll
    for (int j = 0; j < 4; ++j) {
        float4 v = pred4[j * 32];
        p2[2 * j]     = f2{v.x * LOG2E, v.y * LOG2E};
        p2[2 * j + 1] = f2{v.z * LOG2E, v.w * LOG2E};
    }

    // fk_pos (both 32-lane groups compute the identical value concurrently;
    // after the 5-step group reduce it is uniform across the wave)
    float fk_pos;
    {
        const float4* pos4 = (const float4*)(ps + ((size_t)t * B + b) * D) + q;
        float4 ypos[4];
#pragma unroll
        for (int j = 0; j < 4; ++j) ypos[j] = pos4[j * 32];
        float s = buf16(ypos, p2);
#pragma unroll
        for (int off = 1; off < 32; off <<= 1) s += __shfl_xor(s, off, 64);
        fk_pos = s;
    }

    __syncthreads();          // addresses staged

    float negsum = 0.0f;
    bool  all_ok = true;

    float4 Y0[4], Y1[4], Y2[4], Y3[4];

    // stage st (0..15) handles neg n = wave*32 + st*2 + g
#define LOADS(BUF, ST)                                                      \
    {                                                                       \
        const float4* r4_ = (const float4*)s_row[wave * 32 + (ST) * 2 + g] + q; \
        BUF[0] = r4_[0];  BUF[1] = r4_[32];                                 \
        BUF[2] = r4_[64]; BUF[3] = r4_[96];                                 \
    }
#define CONSUME(BUF)                                                        \
    {                                                                       \
        float fk_ = buf16(BUF, p2);                                         \
        _Pragma("unroll")                                                   \
        for (int off_ = 1; off_ < 32; off_ <<= 1)                           \
            fk_ += __shfl_xor(fk_, off_, 64);                               \
        negsum += fk_;                                                      \
        all_ok  = all_ok && (fk_pos > fk_);                                 \
    }

    LOADS(Y0, 0);
    LOADS(Y1, 1);
    LOADS(Y2, 2);

#pragma unroll 1
    for (int it = 0; it < 16; it += 4) {
        LOADS(Y3, it + 3);
        CONSUME(Y0);
        if (it + 4 < 16) LOADS(Y0, it + 4);
        CONSUME(Y1);
        if (it + 5 < 16) LOADS(Y1, it + 5);
        CONSUME(Y2);
        if (it + 6 < 16) LOADS(Y2, it + 6);
        CONSUME(Y3);
    }
#undef LOADS
#undef CONSUME

    const int wave_ok = __all(all_ok ? 1 : 0);
    // Cross-group combine only (offset 32): exact wave total, 1 shuffle.
    float ns = negsum + __shfl_xor(negsum, 32, 64);

    if (lane == 0) { s_sum[wave] = ns; s_ok[wave] = wave_ok; }
    __syncthreads();
    if (tid == 0) {
        float total_neg = (s_sum[0] + s_sum[1]) + (s_sum[2] + s_sum[3]);
        int   ok        = s_ok[0] & s_ok[1] & s_ok[2] & s_ok[3];
        float total     = fk_pos + total_neg;
        float lg = (__builtin_amdgcn_logf(fk_pos) - __builtin_amdgcn_logf(total)) * LN2;
        per_step[tb] = lg;
        flags[tb]    = (float)ok;
    }
}

// Block 0: loss; blocks 1..12: correct_predictions[t]
__global__ __launch_bounds__(256) void reduce_kernel(
    const float* __restrict__ per_step,
    const float* __restrict__ flags,
    float* __restrict__ out)
{
    const int tid = threadIdx.x;
    const int j   = blockIdx.x;
    __shared__ float sh[4];

    float s = 0.0f;
    if (j == 0) {
#pragma unroll
        for (int t = 0; t < N_PRED; ++t) s += per_step[t * B + tid];
    } else {
        s = flags[(j - 1) * B + tid];
    }
#pragma unroll
    for (int off = 32; off > 0; off >>= 1) s += __shfl_xor(s, off, 64);
    if ((tid & 63) == 0) sh[tid >> 6] = s;
    __syncthreads();
    if (tid == 0) {
        float tot = (sh[0] + sh[1]) + (sh[2] + sh[3]);
        if (j == 0)
            out[0] = tot * (1.0f / ((float)(N_NEG + 1) * N_PRED * B));
        else
            out[j] = tot;
    }
}

extern "C" void kernel_launch(void* const* d_in, const int* in_sizes, int n_in,
                              void* d_out, int out_size, void* d_ws, size_t ws_size,
                              hipStream_t stream) {
    const float* lp        = (const float*)d_in[0];
    const float* ps        = (const float*)d_in[1];
    const int*   time_idx  = (const int*)d_in[2];
    const int*   batch_idx = (const int*)d_in[3];
    float* out = (float*)d_out;

    float* per_step = (float*)d_ws;
    float* flags    = per_step + N_PRED * B;

    fk_kernel<<<N_PRED * B, 256, 0, stream>>>(lp, ps, time_idx, batch_idx,
                                              per_step, flags);
    reduce_kernel<<<1 + N_PRED, 256, 0, stream>>>(per_step, flags, out);
}